// Round 10
// baseline (36533.594 us; speedup 1.0000x reference)
//
#include <hip/hip_runtime.h>
#include <math.h>

#define B 512
#define S 256
#define D 64
#define H 512
#define BH (B*H)

typedef __attribute__((ext_vector_type(8))) short short8;
typedef __attribute__((ext_vector_type(4))) float f32x4;

__device__ inline unsigned short f2bf(float v) {            // fp32 -> bf16 RNE
    unsigned int u = __float_as_uint(v);
    unsigned int r = (u + 0x7fffu + ((u >> 16) & 1u)) >> 16;
    return (unsigned short)r;
}
__device__ inline float bf2f(unsigned short b) {
    return __uint_as_float(((unsigned int)b) << 16);
}

// -------- group barrier: 64 WGs, 2-level (8 shards x 8) ---------------------
// per-group region: 256 uints (1KB). shards at s*16, done at 128, gen at 192.
__device__ inline void group_barrier(unsigned int* bar, int grp, int jt) {
    __syncthreads();
    if (threadIdx.x == 0) {
        __threadfence();   // release (cross-XCD writeback)
        unsigned int* base = bar + grp*256;
        unsigned int* gen  = base + 192;
        unsigned int g0 = __hip_atomic_load(gen, __ATOMIC_RELAXED,
                                            __HIP_MEMORY_SCOPE_AGENT);
        unsigned int a = __hip_atomic_fetch_add(base + (jt & 7)*16, 1u,
                             __ATOMIC_ACQ_REL, __HIP_MEMORY_SCOPE_AGENT);
        bool rel = false;
        if (a == 7u) {
            __hip_atomic_store(base + (jt & 7)*16, 0u, __ATOMIC_RELAXED,
                               __HIP_MEMORY_SCOPE_AGENT);
            unsigned int d = __hip_atomic_fetch_add(base + 128, 1u,
                                 __ATOMIC_ACQ_REL, __HIP_MEMORY_SCOPE_AGENT);
            if (d == 7u) {
                __hip_atomic_store(base + 128, 0u, __ATOMIC_RELAXED,
                                   __HIP_MEMORY_SCOPE_AGENT);
                __hip_atomic_store(gen, g0 + 1u, __ATOMIC_RELEASE,
                                   __HIP_MEMORY_SCOPE_AGENT);
                rel = true;
            }
        }
        if (!rel) {
            unsigned int spin = 0;
            while (__hip_atomic_load(gen, __ATOMIC_RELAXED,
                                     __HIP_MEMORY_SCOPE_AGENT) == g0) {
                __builtin_amdgcn_s_sleep(1);
                if (++spin > (1u << 22)) break;   // bail-out: no hang
            }
        }
        __threadfence();   // acquire
    }
    __syncthreads();
}

// ---------------- fallback-path kernels (R7, proven PASS) ----------------
__global__ __launch_bounds__(256) void init_zero(
    float* __restrict__ h32, float* __restrict__ c32,
    unsigned short* __restrict__ hHi, unsigned short* __restrict__ hLo)
{
    int i = blockIdx.x * blockDim.x + threadIdx.x;
    if (i < BH) { h32[i] = 0.f; c32[i] = 0.f; hHi[i] = 0; hLo[i] = 0; }
}

__global__ __launch_bounds__(256) void prep_weights(
    const float* __restrict__ Whh, const float* __restrict__ Wih,
    unsigned short* __restrict__ wswz)
{
    const int jt = blockIdx.x;
    const int kb = blockIdx.y;
    const int t = threadIdx.x;
    const int jj = t >> 3;
    const int kk8 = t & 7;
    const int jg = jt*32 + jj;
    const int u = jg >> 2, q = jg & 3;
    const int Wrow = q*H + u;

    const float* src = (kb < 8) ? (Whh + (size_t)Wrow*H + kb*64 + kk8*8)
                                : (Wih + (size_t)Wrow*D + kk8*8);
    float v[8];
    *(float4*)&v[0] = *(const float4*)(src);
    *(float4*)&v[4] = *(const float4*)(src + 4);

    unsigned short hi[8], lo[8];
    #pragma unroll
    for (int e = 0; e < 8; ++e) {
        hi[e] = f2bf(v[e]);
        lo[e] = f2bf(v[e] - bf2f(hi[e]));
    }
    const int ks = kk8 >> 2, cg2 = kk8 & 3;
    const size_t slab = (size_t)(jt*9 + kb) * 4096;
    *(short8*)(wswz + slab + (size_t)(0*2048 + ks*1024 + cg2*256 + jj*8)) = *(const short8*)hi;
    *(short8*)(wswz + slab + (size_t)(1*2048 + ks*1024 + cg2*256 + jj*8)) = *(const short8*)lo;
}

__global__ __launch_bounds__(256) void attn_kernel(
    const float* __restrict__ x, const float* __restrict__ Wa,
    const float* __restrict__ Ua, const float* __restrict__ ba,
    const float* __restrict__ Va,
    const float* __restrict__ h32, const float* __restrict__ c32,
    unsigned short* __restrict__ xHi, unsigned short* __restrict__ xLo, int t)
{
    const int d = threadIdx.x & 63;
    const int r = (threadIdx.x >> 6) & 1;
    const int p = threadIdx.x >> 7;
    const int b = blockIdx.x * 2 + r;

    const int rd = t & 1;
    const float* __restrict__ hrow = h32 + (size_t)rd*BH + (size_t)b*H;
    const float* __restrict__ crow = c32 + (size_t)b*H;
    const float* __restrict__ xrow = x + ((size_t)b*S + t)*D;

    __shared__ float part[2][2][64];
    __shared__ float ta[2][64];
    __shared__ float pv[2][2][64];

    float a = 0.f;
    if (p == 0) {
        a = ba[d];
        #pragma unroll 8
        for (int k = 0; k < D; ++k) a += xrow[k] * Wa[k*D + d];
        #pragma unroll 8
        for (int k = 0; k < H; ++k) a += hrow[k] * Ua[k*D + d];
    } else {
        #pragma unroll 8
        for (int k = 0; k < H; ++k) a += crow[k] * Ua[(size_t)(H + k)*D + d];
    }
    part[r][p][d] = a;
    __syncthreads();
    if (p == 0) ta[r][d] = tanhf(part[r][0][d] + part[r][1][d]);
    __syncthreads();
    float av = 0.f;
    {
        const int k0 = p * 32;
        #pragma unroll 8
        for (int k = k0; k < k0 + 32; ++k) av += ta[r][k] * Va[k*D + d];
    }
    pv[r][p][d] = av;
    __syncthreads();
    float v = pv[r][0][d] + pv[r][1][d];
    float m = v;
    #pragma unroll
    for (int o = 32; o > 0; o >>= 1) m = fmaxf(m, __shfl_xor(m, o));
    float e = expf(v - m);
    float ssum = e;
    #pragma unroll
    for (int o = 32; o > 0; o >>= 1) ssum += __shfl_xor(ssum, o);
    if (p == 0) {
        float val = (e / ssum) * xrow[d];
        unsigned short hi = f2bf(val);
        unsigned short lo = f2bf(val - bf2f(hi));
        xHi[(size_t)b*D + d] = hi;
        xLo[(size_t)b*D + d] = lo;
    }
}

__global__ __launch_bounds__(256, 2) void gates_kernel(
    const unsigned short* __restrict__ wswz,
    const unsigned short* __restrict__ hHi, const unsigned short* __restrict__ hLo,
    const unsigned short* __restrict__ xHi, const unsigned short* __restrict__ xLo,
    float* __restrict__ h32, float* __restrict__ c32,
    const float* __restrict__ bih, const float* __restrict__ bhh, int t)
{
    const int tid = threadIdx.x;
    const int lane = tid & 63;
    const int wid = tid >> 6;
    const int wr = wid >> 1, wc = wid & 1;
    const int jt = blockIdx.x;
    const int b0 = blockIdx.y * 64;
    const int l15 = lane & 15;
    const int cgi = lane >> 4;

    __shared__ __align__(16) unsigned short aHi[2][64][72];
    __shared__ __align__(16) unsigned short aLo[2][64][72];
    __shared__ float gout[64][37];

    const int rd = t & 1, wrs = rd ^ 1;
    const unsigned short* __restrict__ hHiR = hHi + (size_t)rd*BH;
    const unsigned short* __restrict__ hLoR = hLo + (size_t)rd*BH;

    const int srow = tid >> 2;
    const int q4 = tid & 3;

    {
        const size_t base = (size_t)(b0 + srow)*H + q4*16;
        *(short8*)&aHi[0][srow][q4*16]     = *(const short8*)(hHiR + base);
        *(short8*)&aHi[0][srow][q4*16 + 8] = *(const short8*)(hHiR + base + 8);
        *(short8*)&aLo[0][srow][q4*16]     = *(const short8*)(hLoR + base);
        *(short8*)&aLo[0][srow][q4*16 + 8] = *(const short8*)(hLoR + base + 8);
    }
    __syncthreads();

    f32x4 acc0 = {0,0,0,0}, acc1 = {0,0,0,0};
    const int lofs = cgi*256 + (wc*16 + l15)*8;

    for (int kb = 0; kb < 9; ++kb) {
        const int cur = kb & 1;
        const unsigned short* pB = wswz + (size_t)(jt*9 + kb)*4096;
        short8 bh0 = *(const short8*)(pB + 0*2048 + 0*1024 + lofs);
        short8 bh1 = *(const short8*)(pB + 0*2048 + 1*1024 + lofs);
        short8 bl0 = *(const short8*)(pB + 1*2048 + 0*1024 + lofs);
        short8 bl1 = *(const short8*)(pB + 1*2048 + 1*1024 + lofs);
        if (kb < 8) {
            const unsigned short *sh, *sl;
            if (kb + 1 < 8) {
                const size_t base = (size_t)(b0 + srow)*H + (kb + 1)*64 + q4*16;
                sh = hHiR + base; sl = hLoR + base;
            } else {
                const size_t base = (size_t)(b0 + srow)*D + q4*16;
                sh = xHi + base; sl = xLo + base;
            }
            *(short8*)&aHi[cur^1][srow][q4*16]     = *(const short8*)sh;
            *(short8*)&aHi[cur^1][srow][q4*16 + 8] = *(const short8*)(sh + 8);
            *(short8*)&aLo[cur^1][srow][q4*16]     = *(const short8*)sl;
            *(short8*)&aLo[cur^1][srow][q4*16 + 8] = *(const short8*)(sl + 8);
        }
        const int ar = wr*32 + l15;
        short8 ah00 = *(const short8*)&aHi[cur][ar     ][cgi*8];
        short8 ah01 = *(const short8*)&aHi[cur][ar     ][32 + cgi*8];
        short8 ah10 = *(const short8*)&aHi[cur][ar + 16][cgi*8];
        short8 ah11 = *(const short8*)&aHi[cur][ar + 16][32 + cgi*8];
        short8 al00 = *(const short8*)&aLo[cur][ar     ][cgi*8];
        short8 al01 = *(const short8*)&aLo[cur][ar     ][32 + cgi*8];
        short8 al10 = *(const short8*)&aLo[cur][ar + 16][cgi*8];
        short8 al11 = *(const short8*)&aLo[cur][ar + 16][32 + cgi*8];

        acc0 = __builtin_amdgcn_mfma_f32_16x16x32_bf16(ah00, bh0, acc0, 0,0,0);
        acc1 = __builtin_amdgcn_mfma_f32_16x16x32_bf16(ah10, bh0, acc1, 0,0,0);
        acc0 = __builtin_amdgcn_mfma_f32_16x16x32_bf16(ah00, bl0, acc0, 0,0,0);
        acc1 = __builtin_amdgcn_mfma_f32_16x16x32_bf16(ah10, bl0, acc1, 0,0,0);
        acc0 = __builtin_amdgcn_mfma_f32_16x16x32_bf16(al00, bh0, acc0, 0,0,0);
        acc1 = __builtin_amdgcn_mfma_f32_16x16x32_bf16(al10, bh0, acc1, 0,0,0);
        acc0 = __builtin_amdgcn_mfma_f32_16x16x32_bf16(ah01, bh1, acc0, 0,0,0);
        acc1 = __builtin_amdgcn_mfma_f32_16x16x32_bf16(ah11, bh1, acc1, 0,0,0);
        acc0 = __builtin_amdgcn_mfma_f32_16x16x32_bf16(ah01, bl1, acc0, 0,0,0);
        acc1 = __builtin_amdgcn_mfma_f32_16x16x32_bf16(ah11, bl1, acc1, 0,0,0);
        acc0 = __builtin_amdgcn_mfma_f32_16x16x32_bf16(al01, bh1, acc0, 0,0,0);
        acc1 = __builtin_amdgcn_mfma_f32_16x16x32_bf16(al11, bh1, acc1, 0,0,0);
        __syncthreads();
    }

    {
        const int m0 = cgi * 4;
        #pragma unroll
        for (int r = 0; r < 4; ++r) {
            gout[wr*32 + m0 + r     ][wc*16 + l15] = acc0[r];
            gout[wr*32 + 16 + m0 + r][wc*16 + l15] = acc1[r];
        }
    }
    __syncthreads();
    {
        const int u8 = tid & 7;
        const int u_glob = jt*8 + u8;
        const float bs0 = bih[0*H + u_glob] + bhh[0*H + u_glob];
        const float bs1 = bih[1*H + u_glob] + bhh[1*H + u_glob];
        const float bs2 = bih[2*H + u_glob] + bhh[2*H + u_glob];
        const float bs3 = bih[3*H + u_glob] + bhh[3*H + u_glob];
        float* __restrict__ h32w = h32 + (size_t)wrs*BH;
        unsigned short* __restrict__ hHiW = (unsigned short*)hHi + (size_t)wrs*BH;
        unsigned short* __restrict__ hLoW = (unsigned short*)hLo + (size_t)wrs*BH;
        #pragma unroll
        for (int pp = 0; pp < 2; ++pp) {
            const int row_loc = (tid >> 3) + pp*32;
            const int b = b0 + row_loc;
            float gi = gout[row_loc][u8*4 + 0] + bs0;
            float gf = gout[row_loc][u8*4 + 1] + bs1;
            float gg = gout[row_loc][u8*4 + 2] + bs2;
            float go = gout[row_loc][u8*4 + 3] + bs3;
            const size_t idx = (size_t)b*H + u_glob;
            float c_old = c32[idx];
            float si = 1.f/(1.f + expf(-gi));
            float sf = 1.f/(1.f + expf(-gf));
            float so = 1.f/(1.f + expf(-go));
            float cn = sf*c_old + si*tanhf(gg);
            float hn = so*tanhf(cn);
            c32[idx] = cn;
            h32w[idx] = hn;
            unsigned short hi = f2bf(hn);
            unsigned short lo = f2bf(hn - bf2f(hi));
            hHiW[idx] = hi;
            hLoW[idx] = lo;
        }
    }
}

// ---------------- persistent kernel, GROUP-LOCAL sync ----------------
// 8 groups (rt) x 64 WGs (jt) x 64 rows. bid = rt*64 + jt.
__global__ __launch_bounds__(256, 2) void persist_kernel(
    const float* __restrict__ x, const float* __restrict__ Wa,
    const float* __restrict__ Ua, const float* __restrict__ ba,
    const float* __restrict__ Va,
    const unsigned short* __restrict__ wswz,
    unsigned short* __restrict__ hHi, unsigned short* __restrict__ hLo,
    unsigned short* __restrict__ xHi, unsigned short* __restrict__ xLo,
    float* __restrict__ h32, float* __restrict__ c32,
    const float* __restrict__ bih, const float* __restrict__ bhh,
    float* __restrict__ partials, unsigned int* bar)
{
    const int g = blockIdx.x;
    const int tid = threadIdx.x;
    const int lane = tid & 63;
    const int rt = g >> 6;
    const int jt = g & 63;
    const int r0 = rt * 64;
    const int b0 = r0;

    __shared__ __align__(16) unsigned short aHi[2][64][72];   // 18.4 KB
    __shared__ __align__(16) unsigned short aLo[2][64][72];   // 18.4 KB
    __shared__ float gout[64][37];                            //  9.5 KB
    float* hcS = (float*)&aHi[0][0][0];   // A1 slice [64][69] f32 (17.7KB, fits)
    float* p2  = (float*)&aLo[0][0][0];   // A2: [4][64] partial sums
    float* taL = p2 + 256;                // A2: ta[64]

    const int wid = tid >> 6;
    const int wr = wid >> 1, wc = wid & 1;
    const int l15 = lane & 15;
    const int cgi = lane >> 4;
    const int srow = tid >> 2;
    const int q4 = tid & 3;
    const int lofs = cgi*256 + (wc*16 + l15)*8;

    // init: WG jt zeroes state of its row r0+jt (slot 0)
    {
        const int b = r0 + jt;
        float* hp = h32 + (size_t)b*H;
        float* cp = c32 + (size_t)b*H;
        unsigned short* hh = hHi + (size_t)b*H;
        unsigned short* hl = hLo + (size_t)b*H;
        for (int i = tid; i < H; i += 256) { hp[i] = 0.f; cp[i] = 0.f; hh[i] = 0; hl[i] = 0; }
    }
    group_barrier(bar, rt, jt);

    for (int ts = 0; ts < S; ++ts) {
        const int rd = ts & 1, wrs = rd ^ 1;
        const float* __restrict__ h32r = h32 + (size_t)rd*BH;
        const unsigned short* __restrict__ hHiR = hHi + (size_t)rd*BH;
        const unsigned short* __restrict__ hLoR = hLo + (size_t)rd*BH;

        // ---- A1: attn partials, WGs jt<16, k-slice jt*68..+68 over [x|h|c]
        if (jt < 16) {
            const int k0 = jt * 68;
            for (int i = tid; i < 64*68; i += 256) {
                const int row = i / 68, kk = i - row*68;
                const int k = k0 + kk;
                float v;
                if (k < 64)       v = x[((size_t)(r0+row)*S + ts)*D + k];
                else if (k < 576) v = h32r[(size_t)(r0+row)*H + (k - 64)];
                else              v = c32[(size_t)(r0+row)*H + (k - 576)];
                hcS[row*69 + kk] = v;
            }
            __syncthreads();
            const int d = tid & 63, rq = tid >> 6;
            float acc[16];
            #pragma unroll
            for (int r = 0; r < 16; ++r) acc[r] = 0.f;
            for (int kk = 0; kk < 68; ++kk) {
                const int k = k0 + kk;
                const float uv = (k < 64) ? Wa[k*D + d] : Ua[(size_t)(k - 64)*D + d];
                #pragma unroll
                for (int r = 0; r < 16; ++r)
                    acc[r] += hcS[(rq*16 + r)*69 + kk] * uv;
            }
            float* pout = partials + ((size_t)(rt*16 + jt)*64)*64;
            #pragma unroll
            for (int r = 0; r < 16; ++r)
                pout[(rq*16 + r)*64 + d] = acc[r];
        }
        group_barrier(bar, rt, jt);            // bar1: partials ready

        // ---- A2: every WG finishes attn for its own row b = r0 + jt
        {
            const int b = r0 + jt;
            const int d = tid & 63, w4 = tid >> 6;
            float s = 0.f;
            #pragma unroll
            for (int w = 0; w < 4; ++w)
                s += partials[((size_t)(rt*16 + (w4*4 + w))*64 + jt)*64 + d];
            p2[w4*64 + d] = s;
            __syncthreads();
            if (tid < 64) {
                float apre = p2[tid] + p2[64 + tid] + p2[128 + tid] + p2[192 + tid] + ba[tid];
                taL[tid] = tanhf(apre);
            }
            __syncthreads();
            if (tid < 64) {
                float av = 0.f;
                #pragma unroll 8
                for (int k = 0; k < 64; ++k) av += taL[k] * Va[k*D + tid];
                float m = av;
                #pragma unroll
                for (int o = 32; o > 0; o >>= 1) m = fmaxf(m, __shfl_xor(m, o));
                float e = expf(av - m);
                float ss = e;
                #pragma unroll
                for (int o = 32; o > 0; o >>= 1) ss += __shfl_xor(ss, o);
                float val = (e / ss) * x[((size_t)b*S + ts)*D + tid];
                unsigned short hi = f2bf(val);
                xHi[(size_t)b*D + tid] = hi;
                xLo[(size_t)b*D + tid] = f2bf(val - bf2f(hi));
            }
            __syncthreads();   // taL/p2 done; LDS free for B staging
        }

        // ---- B: gate GEMM (R7 body) with xatt-barrier before chunk-8 prefetch
        {
            const size_t basea = (size_t)(b0 + srow)*H + q4*16;
            *(short8*)&aHi[0][srow][q4*16]     = *(const short8*)(hHiR + basea);
            *(short8*)&aHi[0][srow][q4*16 + 8] = *(const short8*)(hHiR + basea + 8);
            *(short8*)&aLo[0][srow][q4*16]     = *(const short8*)(hLoR + basea);
            *(short8*)&aLo[0][srow][q4*16 + 8] = *(const short8*)(hLoR + basea + 8);
        }
        __syncthreads();

        f32x4 acc0 = {0,0,0,0}, acc1 = {0,0,0,0};

        for (int kb = 0; kb < 9; ++kb) {
            if (kb == 7) group_barrier(bar, rt, jt);   // bar2: xatt visible
            const int cur = kb & 1;
            const unsigned short* pB = wswz + (size_t)(jt*9 + kb)*4096;
            short8 bh0 = *(const short8*)(pB + 0*2048 + 0*1024 + lofs);
            short8 bh1 = *(const short8*)(pB + 0*2048 + 1*1024 + lofs);
            short8 bl0 = *(const short8*)(pB + 1*2048 + 0*1024 + lofs);
            short8 bl1 = *(const short8*)(pB + 1*2048 + 1*1024 + lofs);
            if (kb < 8) {
                const unsigned short *sh, *sl;
                if (kb + 1 < 8) {
                    const size_t base = (size_t)(b0 + srow)*H + (kb + 1)*64 + q4*16;
                    sh = hHiR + base; sl = hLoR + base;
                } else {
                    const size_t base = (size_t)(b0 + srow)*D + q4*16;
                    sh = xHi + base; sl = xLo + base;
                }
                *(short8*)&aHi[cur^1][srow][q4*16]     = *(const short8*)sh;
                *(short8*)&aHi[cur^1][srow][q4*16 + 8] = *(const short8*)(sh + 8);
                *(short8*)&aLo[cur^1][srow][q4*16]     = *(const short8*)sl;
                *(short8*)&aLo[cur^1][srow][q4*16 + 8] = *(const short8*)(sl + 8);
            }
            const int ar = wr*32 + l15;
            short8 ah00 = *(const short8*)&aHi[cur][ar     ][cgi*8];
            short8 ah01 = *(const short8*)&aHi[cur][ar     ][32 + cgi*8];
            short8 ah10 = *(const short8*)&aHi[cur][ar + 16][cgi*8];
            short8 ah11 = *(const short8*)&aHi[cur][ar + 16][32 + cgi*8];
            short8 al00 = *(const short8*)&aLo[cur][ar     ][cgi*8];
            short8 al01 = *(const short8*)&aLo[cur][ar     ][32 + cgi*8];
            short8 al10 = *(const short8*)&aLo[cur][ar + 16][cgi*8];
            short8 al11 = *(const short8*)&aLo[cur][ar + 16][32 + cgi*8];

            acc0 = __builtin_amdgcn_mfma_f32_16x16x32_bf16(ah00, bh0, acc0, 0,0,0);
            acc1 = __builtin_amdgcn_mfma_f32_16x16x32_bf16(ah10, bh0, acc1, 0,0,0);
            acc0 = __builtin_amdgcn_mfma_f32_16x16x32_bf16(ah00, bl0, acc0, 0,0,0);
            acc1 = __builtin_amdgcn_mfma_f32_16x16x32_bf16(ah10, bl0, acc1, 0,0,0);
            acc0 = __builtin_amdgcn_mfma_f32_16x16x32_bf16(al00, bh0, acc0, 0,0,0);
            acc1 = __builtin_amdgcn_mfma_f32_16x16x32_bf16(al10, bh0, acc1, 0,0,0);
            acc0 = __builtin_amdgcn_mfma_f32_16x16x32_bf16(ah01, bh1, acc0, 0,0,0);
            acc1 = __builtin_amdgcn_mfma_f32_16x16x32_bf16(ah11, bh1, acc1, 0,0,0);
            acc0 = __builtin_amdgcn_mfma_f32_16x16x32_bf16(ah01, bl1, acc0, 0,0,0);
            acc1 = __builtin_amdgcn_mfma_f32_16x16x32_bf16(ah11, bl1, acc1, 0,0,0);
            acc0 = __builtin_amdgcn_mfma_f32_16x16x32_bf16(al01, bh1, acc0, 0,0,0);
            acc1 = __builtin_amdgcn_mfma_f32_16x16x32_bf16(al11, bh1, acc1, 0,0,0);
            __syncthreads();
        }

        {
            const int m0 = cgi * 4;
            #pragma unroll
            for (int r = 0; r < 4; ++r) {
                gout[wr*32 + m0 + r     ][wc*16 + l15] = acc0[r];
                gout[wr*32 + 16 + m0 + r][wc*16 + l15] = acc1[r];
            }
        }
        __syncthreads();
        {
            const int u8 = tid & 7;
            const int u_glob = jt*8 + u8;
            const float bs0 = bih[0*H + u_glob] + bhh[0*H + u_glob];
            const float bs1 = bih[1*H + u_glob] + bhh[1*H + u_glob];
            const float bs2 = bih[2*H + u_glob] + bhh[2*H + u_glob];
            const float bs3 = bih[3*H + u_glob] + bhh[3*H + u_glob];
            float* __restrict__ h32w = h32 + (size_t)wrs*BH;
            unsigned short* __restrict__ hHiW = hHi + (size_t)wrs*BH;
            unsigned short* __restrict__ hLoW = hLo + (size_t)wrs*BH;
            #pragma unroll
            for (int pp = 0; pp < 2; ++pp) {
                const int row_loc = (tid >> 3) + pp*32;
                const int b = b0 + row_loc;
                float gi = gout[row_loc][u8*4 + 0] + bs0;
                float gf = gout[row_loc][u8*4 + 1] + bs1;
                float ggt = gout[row_loc][u8*4 + 2] + bs2;
                float go = gout[row_loc][u8*4 + 3] + bs3;
                const size_t idx = (size_t)b*H + u_glob;
                float c_old = c32[idx];
                float si = 1.f/(1.f + expf(-gi));
                float sf = 1.f/(1.f + expf(-gf));
                float so = 1.f/(1.f + expf(-go));
                float cn = sf*c_old + si*tanhf(ggt);
                float hn = so*tanhf(cn);
                c32[idx] = cn;
                h32w[idx] = hn;
                unsigned short hi = f2bf(hn);
                unsigned short lo = f2bf(hn - bf2f(hi));
                hHiW[idx] = hi;
                hLoW[idx] = lo;
            }
        }
        group_barrier(bar, rt, jt);            // bar3: h(t+1)/c(t+1) visible
    }
}

__global__ __launch_bounds__(256) void fc_kernel(
    const float* __restrict__ fcw, const float* __restrict__ fcb,
    const float* __restrict__ h32, float* __restrict__ out)
{
    const int b = blockIdx.x;
    __shared__ float hrow[H];
    const float* __restrict__ hp = h32 + (size_t)b*H;   // final h in slot 0
    for (int k = threadIdx.x; k < H; k += 256) hrow[k] = hp[k];
    __syncthreads();
    int j = threadIdx.x;
    if (j < 24) {
        float a = fcb[j];
        #pragma unroll 8
        for (int k = 0; k < H; ++k) a += hrow[k] * fcw[j*H + k];
        out[b*24 + j] = a;
    }
}

extern "C" void kernel_launch(void* const* d_in, const int* in_sizes, int n_in,
                              void* d_out, int out_size, void* d_ws, size_t ws_size,
                              hipStream_t stream) {
    const float* x   = (const float*)d_in[0];
    const float* Wa  = (const float*)d_in[1];
    const float* Ua  = (const float*)d_in[2];
    const float* ba  = (const float*)d_in[3];
    const float* Va  = (const float*)d_in[4];
    const float* Wih = (const float*)d_in[5];
    const float* Whh = (const float*)d_in[6];
    const float* bih = (const float*)d_in[7];
    const float* bhh = (const float*)d_in[8];
    const float* fcw = (const float*)d_in[9];
    const float* fcb = (const float*)d_in[10];
    float* out = (float*)d_out;

    char* base = (char*)d_ws;
    float* h32 = (float*)(base);                                    // 2MB
    float* c32 = (float*)(base + (size_t)2*BH*4);                   // 1MB
    unsigned short* hHi = (unsigned short*)(base + (size_t)3*BH*4); // 1MB
    unsigned short* hLo = hHi + (size_t)2*BH;                       // 1MB
    unsigned short* xHi = hLo + (size_t)2*BH;                       // 64KB
    unsigned short* xLo = xHi + (size_t)B*D;                        // 64KB
    unsigned short* wswz = xLo + (size_t)B*D;                       // 4.5MB
    unsigned int* bar = (unsigned int*)(wswz + (size_t)576*4096);   // 8KB
    float* partials = (float*)((char*)bar + 8192);                  // 2MB
    const size_t NEED = ((char*)partials - base) + (size_t)128*64*64*4;

    hipLaunchKernelGGL(prep_weights, dim3(64, 9), dim3(256), 0, stream,
                       Whh, Wih, wswz);

    bool coop = (ws_size >= NEED);
    if (coop) {
        int maxBlk = 0;
        hipError_t oe = hipOccupancyMaxActiveBlocksPerMultiprocessor(
            &maxBlk, persist_kernel, 256, 0);
        coop = (oe == hipSuccess && maxBlk >= 2);
    }
    if (coop) {
        hipMemsetAsync(bar, 0, 8192, stream);
        void* args[] = {
            (void*)&x, (void*)&Wa, (void*)&Ua, (void*)&ba, (void*)&Va,
            (void*)&wswz, (void*)&hHi, (void*)&hLo, (void*)&xHi, (void*)&xLo,
            (void*)&h32, (void*)&c32, (void*)&bih, (void*)&bhh,
            (void*)&partials, (void*)&bar
        };
        hipError_t rc = hipLaunchCooperativeKernel((void*)persist_kernel,
                            dim3(512), dim3(256), args, 0, stream);
        if (rc != hipSuccess) coop = false;
    }
    if (!coop) {   // fallback: proven multi-kernel path (R7)
        hipLaunchKernelGGL(init_zero, dim3((BH + 255)/256), dim3(256), 0, stream,
                           h32, c32, hHi, hLo);
        for (int t = 0; t < S; ++t) {
            hipLaunchKernelGGL(attn_kernel, dim3(B/2), dim3(256), 0, stream,
                               x, Wa, Ua, ba, Va, h32, c32, xHi, xLo, t);
            hipLaunchKernelGGL(gates_kernel, dim3(64, 8), dim3(256), 0, stream,
                               wswz, hHi, hLo, xHi, xLo, h32, c32, bih, bhh, t);
        }
    }
    hipLaunchKernelGGL(fc_kernel, dim3(B), dim3(256), 0, stream, fcw, fcb, h32, out);
}

// Round 11
// 8611.658 us; speedup vs baseline: 4.2423x; 4.2423x over previous
//
#include <hip/hip_runtime.h>
#include <math.h>

#define B 512
#define S 256
#define D 64
#define H 512
#define BH (B*H)

typedef __attribute__((ext_vector_type(8))) short short8;
typedef __attribute__((ext_vector_type(4))) float f32x4;

__device__ inline unsigned short f2bf(float v) {            // fp32 -> bf16 RNE
    unsigned int u = __float_as_uint(v);
    unsigned int r = (u + 0x7fffu + ((u >> 16) & 1u)) >> 16;
    return (unsigned short)r;
}
__device__ inline float bf2f(unsigned short b) {
    return __uint_as_float(((unsigned int)b) << 16);
}

// ---- coherent (cross-XCD) access helpers: bypass L1/L2 via sc0 sc1 ----
__device__ inline float ld_sc_f1(const float* p) {
    float r;
    asm volatile("global_load_dword %0, %1, off sc0 sc1\n\ts_waitcnt vmcnt(0)"
                 : "=v"(r) : "v"(p) : "memory");
    return r;
}
__device__ inline float4 ld_sc_f4(const float* p) {
    float4 r;
    asm volatile("global_load_dwordx4 %0, %1, off sc0 sc1\n\ts_waitcnt vmcnt(0)"
                 : "=v"(r) : "v"(p) : "memory");
    return r;
}
__device__ inline void ld_sc_4x16(const unsigned short* ph, const unsigned short* pl,
                                  short8& h0, short8& h1, short8& l0, short8& l1) {
    asm volatile(
        "global_load_dwordx4 %0, %4, off sc0 sc1\n\t"
        "global_load_dwordx4 %1, %4, off offset:16 sc0 sc1\n\t"
        "global_load_dwordx4 %2, %5, off sc0 sc1\n\t"
        "global_load_dwordx4 %3, %5, off offset:16 sc0 sc1\n\t"
        "s_waitcnt vmcnt(0)"
        : "=&v"(h0), "=&v"(h1), "=&v"(l0), "=&v"(l1)
        : "v"(ph), "v"(pl) : "memory");
}
__device__ inline void st_sc_f1(float* p, float v) {
    asm volatile("global_store_dword %0, %1, off sc0 sc1" :: "v"(p), "v"(v) : "memory");
}
__device__ inline void st_sc_s1(unsigned short* p, unsigned short v) {
    unsigned int vv = v;
    asm volatile("global_store_short %0, %1, off sc0 sc1" :: "v"(p), "v"(vv) : "memory");
}
__device__ inline void drain_stores() {
    asm volatile("s_waitcnt vmcnt(0)" ::: "memory");
}

// ---- flag sync: monotonic counters, relaxed agent atomics, NO fences ----
__device__ inline void bump_flag(unsigned int* f) {
    __hip_atomic_fetch_add(f, 1u, __ATOMIC_RELAXED, __HIP_MEMORY_SCOPE_AGENT);
}
__device__ inline void wait_flag(unsigned int* f, unsigned int target) {
    if (threadIdx.x == 0) {
        unsigned int spin = 0;
        while (__hip_atomic_load(f, __ATOMIC_RELAXED, __HIP_MEMORY_SCOPE_AGENT) < target) {
            __builtin_amdgcn_s_sleep(2);
            if (++spin > (1u << 18)) break;   // bail-out: no hang
        }
    }
    __syncthreads();
}

// ---------------- fallback-path kernels (R7, proven PASS) ----------------
__global__ __launch_bounds__(256) void init_zero(
    float* __restrict__ h32, float* __restrict__ c32,
    unsigned short* __restrict__ hHi, unsigned short* __restrict__ hLo)
{
    int i = blockIdx.x * blockDim.x + threadIdx.x;
    if (i < BH) { h32[i] = 0.f; c32[i] = 0.f; hHi[i] = 0; hLo[i] = 0; }
}

__global__ __launch_bounds__(256) void prep_weights(
    const float* __restrict__ Whh, const float* __restrict__ Wih,
    unsigned short* __restrict__ wswz)
{
    const int jt = blockIdx.x;
    const int kb = blockIdx.y;
    const int t = threadIdx.x;
    const int jj = t >> 3;
    const int kk8 = t & 7;
    const int jg = jt*32 + jj;
    const int u = jg >> 2, q = jg & 3;
    const int Wrow = q*H + u;

    const float* src = (kb < 8) ? (Whh + (size_t)Wrow*H + kb*64 + kk8*8)
                                : (Wih + (size_t)Wrow*D + kk8*8);
    float v[8];
    *(float4*)&v[0] = *(const float4*)(src);
    *(float4*)&v[4] = *(const float4*)(src + 4);

    unsigned short hi[8], lo[8];
    #pragma unroll
    for (int e = 0; e < 8; ++e) {
        hi[e] = f2bf(v[e]);
        lo[e] = f2bf(v[e] - bf2f(hi[e]));
    }
    const int ks = kk8 >> 2, cg2 = kk8 & 3;
    const size_t slab = (size_t)(jt*9 + kb) * 4096;
    *(short8*)(wswz + slab + (size_t)(0*2048 + ks*1024 + cg2*256 + jj*8)) = *(const short8*)hi;
    *(short8*)(wswz + slab + (size_t)(1*2048 + ks*1024 + cg2*256 + jj*8)) = *(const short8*)lo;
}

__global__ __launch_bounds__(256) void attn_kernel(
    const float* __restrict__ x, const float* __restrict__ Wa,
    const float* __restrict__ Ua, const float* __restrict__ ba,
    const float* __restrict__ Va,
    const float* __restrict__ h32, const float* __restrict__ c32,
    unsigned short* __restrict__ xHi, unsigned short* __restrict__ xLo, int t)
{
    const int d = threadIdx.x & 63;
    const int r = (threadIdx.x >> 6) & 1;
    const int p = threadIdx.x >> 7;
    const int b = blockIdx.x * 2 + r;

    const int rd = t & 1;
    const float* __restrict__ hrow = h32 + (size_t)rd*BH + (size_t)b*H;
    const float* __restrict__ crow = c32 + (size_t)b*H;
    const float* __restrict__ xrow = x + ((size_t)b*S + t)*D;

    __shared__ float part[2][2][64];
    __shared__ float ta[2][64];
    __shared__ float pv[2][2][64];

    float a = 0.f;
    if (p == 0) {
        a = ba[d];
        #pragma unroll 8
        for (int k = 0; k < D; ++k) a += xrow[k] * Wa[k*D + d];
        #pragma unroll 8
        for (int k = 0; k < H; ++k) a += hrow[k] * Ua[k*D + d];
    } else {
        #pragma unroll 8
        for (int k = 0; k < H; ++k) a += crow[k] * Ua[(size_t)(H + k)*D + d];
    }
    part[r][p][d] = a;
    __syncthreads();
    if (p == 0) ta[r][d] = tanhf(part[r][0][d] + part[r][1][d]);
    __syncthreads();
    float av = 0.f;
    {
        const int k0 = p * 32;
        #pragma unroll 8
        for (int k = k0; k < k0 + 32; ++k) av += ta[r][k] * Va[k*D + d];
    }
    pv[r][p][d] = av;
    __syncthreads();
    float v = pv[r][0][d] + pv[r][1][d];
    float m = v;
    #pragma unroll
    for (int o = 32; o > 0; o >>= 1) m = fmaxf(m, __shfl_xor(m, o));
    float e = expf(v - m);
    float ssum = e;
    #pragma unroll
    for (int o = 32; o > 0; o >>= 1) ssum += __shfl_xor(ssum, o);
    if (p == 0) {
        float val = (e / ssum) * xrow[d];
        unsigned short hi = f2bf(val);
        unsigned short lo = f2bf(val - bf2f(hi));
        xHi[(size_t)b*D + d] = hi;
        xLo[(size_t)b*D + d] = lo;
    }
}

__global__ __launch_bounds__(256, 2) void gates_kernel(
    const unsigned short* __restrict__ wswz,
    const unsigned short* __restrict__ hHi, const unsigned short* __restrict__ hLo,
    const unsigned short* __restrict__ xHi, const unsigned short* __restrict__ xLo,
    float* __restrict__ h32, float* __restrict__ c32,
    const float* __restrict__ bih, const float* __restrict__ bhh, int t)
{
    const int tid = threadIdx.x;
    const int lane = tid & 63;
    const int wid = tid >> 6;
    const int wr = wid >> 1, wc = wid & 1;
    const int jt = blockIdx.x;
    const int b0 = blockIdx.y * 64;
    const int l15 = lane & 15;
    const int cgi = lane >> 4;

    __shared__ __align__(16) unsigned short aHi[2][64][72];
    __shared__ __align__(16) unsigned short aLo[2][64][72];
    __shared__ float gout[64][37];

    const int rd = t & 1, wrs = rd ^ 1;
    const unsigned short* __restrict__ hHiR = hHi + (size_t)rd*BH;
    const unsigned short* __restrict__ hLoR = hLo + (size_t)rd*BH;

    const int srow = tid >> 2;
    const int q4 = tid & 3;

    {
        const size_t base = (size_t)(b0 + srow)*H + q4*16;
        *(short8*)&aHi[0][srow][q4*16]     = *(const short8*)(hHiR + base);
        *(short8*)&aHi[0][srow][q4*16 + 8] = *(const short8*)(hHiR + base + 8);
        *(short8*)&aLo[0][srow][q4*16]     = *(const short8*)(hLoR + base);
        *(short8*)&aLo[0][srow][q4*16 + 8] = *(const short8*)(hLoR + base + 8);
    }
    __syncthreads();

    f32x4 acc0 = {0,0,0,0}, acc1 = {0,0,0,0};
    const int lofs = cgi*256 + (wc*16 + l15)*8;

    for (int kb = 0; kb < 9; ++kb) {
        const int cur = kb & 1;
        const unsigned short* pB = wswz + (size_t)(jt*9 + kb)*4096;
        short8 bh0 = *(const short8*)(pB + 0*2048 + 0*1024 + lofs);
        short8 bh1 = *(const short8*)(pB + 0*2048 + 1*1024 + lofs);
        short8 bl0 = *(const short8*)(pB + 1*2048 + 0*1024 + lofs);
        short8 bl1 = *(const short8*)(pB + 1*2048 + 1*1024 + lofs);
        if (kb < 8) {
            const unsigned short *sh, *sl;
            if (kb + 1 < 8) {
                const size_t base = (size_t)(b0 + srow)*H + (kb + 1)*64 + q4*16;
                sh = hHiR + base; sl = hLoR + base;
            } else {
                const size_t base = (size_t)(b0 + srow)*D + q4*16;
                sh = xHi + base; sl = xLo + base;
            }
            *(short8*)&aHi[cur^1][srow][q4*16]     = *(const short8*)sh;
            *(short8*)&aHi[cur^1][srow][q4*16 + 8] = *(const short8*)(sh + 8);
            *(short8*)&aLo[cur^1][srow][q4*16]     = *(const short8*)sl;
            *(short8*)&aLo[cur^1][srow][q4*16 + 8] = *(const short8*)(sl + 8);
        }
        const int ar = wr*32 + l15;
        short8 ah00 = *(const short8*)&aHi[cur][ar     ][cgi*8];
        short8 ah01 = *(const short8*)&aHi[cur][ar     ][32 + cgi*8];
        short8 ah10 = *(const short8*)&aHi[cur][ar + 16][cgi*8];
        short8 ah11 = *(const short8*)&aHi[cur][ar + 16][32 + cgi*8];
        short8 al00 = *(const short8*)&aLo[cur][ar     ][cgi*8];
        short8 al01 = *(const short8*)&aLo[cur][ar     ][32 + cgi*8];
        short8 al10 = *(const short8*)&aLo[cur][ar + 16][cgi*8];
        short8 al11 = *(const short8*)&aLo[cur][ar + 16][32 + cgi*8];

        acc0 = __builtin_amdgcn_mfma_f32_16x16x32_bf16(ah00, bh0, acc0, 0,0,0);
        acc1 = __builtin_amdgcn_mfma_f32_16x16x32_bf16(ah10, bh0, acc1, 0,0,0);
        acc0 = __builtin_amdgcn_mfma_f32_16x16x32_bf16(ah00, bl0, acc0, 0,0,0);
        acc1 = __builtin_amdgcn_mfma_f32_16x16x32_bf16(ah10, bl0, acc1, 0,0,0);
        acc0 = __builtin_amdgcn_mfma_f32_16x16x32_bf16(al00, bh0, acc0, 0,0,0);
        acc1 = __builtin_amdgcn_mfma_f32_16x16x32_bf16(al10, bh0, acc1, 0,0,0);
        acc0 = __builtin_amdgcn_mfma_f32_16x16x32_bf16(ah01, bh1, acc0, 0,0,0);
        acc1 = __builtin_amdgcn_mfma_f32_16x16x32_bf16(ah11, bh1, acc1, 0,0,0);
        acc0 = __builtin_amdgcn_mfma_f32_16x16x32_bf16(ah01, bl1, acc0, 0,0,0);
        acc1 = __builtin_amdgcn_mfma_f32_16x16x32_bf16(ah11, bl1, acc1, 0,0,0);
        acc0 = __builtin_amdgcn_mfma_f32_16x16x32_bf16(al01, bh1, acc0, 0,0,0);
        acc1 = __builtin_amdgcn_mfma_f32_16x16x32_bf16(al11, bh1, acc1, 0,0,0);
        __syncthreads();
    }

    {
        const int m0 = cgi * 4;
        #pragma unroll
        for (int r = 0; r < 4; ++r) {
            gout[wr*32 + m0 + r     ][wc*16 + l15] = acc0[r];
            gout[wr*32 + 16 + m0 + r][wc*16 + l15] = acc1[r];
        }
    }
    __syncthreads();
    {
        const int u8 = tid & 7;
        const int u_glob = jt*8 + u8;
        const float bs0 = bih[0*H + u_glob] + bhh[0*H + u_glob];
        const float bs1 = bih[1*H + u_glob] + bhh[1*H + u_glob];
        const float bs2 = bih[2*H + u_glob] + bhh[2*H + u_glob];
        const float bs3 = bih[3*H + u_glob] + bhh[3*H + u_glob];
        float* __restrict__ h32w = h32 + (size_t)wrs*BH;
        unsigned short* __restrict__ hHiW = (unsigned short*)hHi + (size_t)wrs*BH;
        unsigned short* __restrict__ hLoW = (unsigned short*)hLo + (size_t)wrs*BH;
        #pragma unroll
        for (int pp = 0; pp < 2; ++pp) {
            const int row_loc = (tid >> 3) + pp*32;
            const int b = b0 + row_loc;
            float gi = gout[row_loc][u8*4 + 0] + bs0;
            float gf = gout[row_loc][u8*4 + 1] + bs1;
            float gg = gout[row_loc][u8*4 + 2] + bs2;
            float go = gout[row_loc][u8*4 + 3] + bs3;
            const size_t idx = (size_t)b*H + u_glob;
            float c_old = c32[idx];
            float si = 1.f/(1.f + expf(-gi));
            float sf = 1.f/(1.f + expf(-gf));
            float so = 1.f/(1.f + expf(-go));
            float cn = sf*c_old + si*tanhf(gg);
            float hn = so*tanhf(cn);
            c32[idx] = cn;
            h32w[idx] = hn;
            unsigned short hi = f2bf(hn);
            unsigned short lo = f2bf(hn - bf2f(hi));
            hHiW[idx] = hi;
            hLoW[idx] = lo;
        }
    }
}

// ------------- persistent kernel: fence-free, flag-synced groups -------------
// 8 independent groups (rt) x 64 blocks (jt). Block owns attn row r0+jt and
// gate-column slice jt (32 j = 8 units). Cross-block state via sc0sc1; weights
// & inputs via normal cached loads (L2 stays warm: no fences ever).
__global__ __launch_bounds__(256, 2) void persist_kernel(
    const float* __restrict__ x, const float* __restrict__ Wa,
    const float* __restrict__ Ua, const float* __restrict__ ba,
    const float* __restrict__ Va,
    const unsigned short* __restrict__ wswz,
    unsigned short* __restrict__ hHi, unsigned short* __restrict__ hLo,
    unsigned short* __restrict__ xHi, unsigned short* __restrict__ xLo,
    float* __restrict__ h32, float* __restrict__ c32,
    const float* __restrict__ bih, const float* __restrict__ bhh,
    unsigned int* bar)
{
    const int g = blockIdx.x;
    const int tid = threadIdx.x;
    const int lane = tid & 63;
    const int rt = g >> 6, jt = g & 63;
    const int r0 = rt * 64, b0 = r0;
    const int row = r0 + jt;

    __shared__ __align__(16) unsigned short aHi[2][64][72];
    __shared__ __align__(16) unsigned short aLo[2][64][72];
    __shared__ float gout[64][37];
    float* arena = &gout[0][0];   // attn scratch: hcx[1088]@0, part@1104, ta@1360

    unsigned int* hflag = bar + rt*16;
    unsigned int* xflag = bar + 128 + rt*16;

    const int wid = tid >> 6;
    const int wr = wid >> 1, wc = wid & 1;
    const int l15 = lane & 15;
    const int cgi = lane >> 4;
    const int srow = tid >> 2;
    const int q4 = tid & 3;
    const int lofs = cgi*256 + (wc*16 + l15)*8;

    // ---- init own row (sc stores so later sc loads observe them) ----
    {
        float* hp = h32 + (size_t)row*H;           // slot 0
        float* cp = c32 + (size_t)row*H;
        unsigned short* hh = hHi + (size_t)row*H;
        unsigned short* hl = hLo + (size_t)row*H;
        for (int i = tid; i < H; i += 256) {
            st_sc_f1(hp + i, 0.f);
            st_sc_f1(cp + i, 0.f);
            st_sc_s1(hh + i, 0);
            st_sc_s1(hl + i, 0);
        }
        drain_stores();
        __syncthreads();
        if (tid == 0) bump_flag(hflag);
    }

    for (int ts = 0; ts < S; ++ts) {
        const int rd = ts & 1, wrs = rd ^ 1;
        const float* h32r = h32 + (size_t)rd*BH;
        const unsigned short* hHiR = hHi + (size_t)rd*BH;
        const unsigned short* hLoR = hLo + (size_t)rd*BH;
        const unsigned int tgt = (unsigned int)(64*(ts + 1));

        wait_flag(hflag, tgt);   // h(ts)/c(ts) published by all 64 group blocks

        // ---- Phase A: attention for own row ----
        for (int c = tid; c < 272; c += 256) {
            float4 v;
            if (c < 16)       v = *(const float4*)(x + ((size_t)row*S + ts)*D + c*4);
            else if (c < 144) v = ld_sc_f4(h32r + (size_t)row*H + (c-16)*4);
            else              v = ld_sc_f4(c32 + (size_t)row*H + (c-144)*4);
            *(float4*)&arena[c*4] = v;
        }
        __syncthreads();
        {
            const int w = wid;
            const int k0 = w * 272;
            float a = 0.f;
            #pragma unroll 4
            for (int kk = 0; kk < 272; ++kk) {
                const int k = k0 + kk;
                const float wv = (k < 64) ? Wa[k*D + lane]
                                          : Ua[(size_t)(k - 64)*D + lane];
                a = fmaf(arena[k], wv, a);
            }
            arena[1104 + w*64 + lane] = a;
        }
        __syncthreads();
        if (wid == 0) {
            float pre = ba[lane] + arena[1104+lane] + arena[1168+lane]
                      + arena[1232+lane] + arena[1296+lane];
            arena[1360 + lane] = tanhf(pre);
        }
        __syncthreads();
        if (wid == 0) {
            float v = 0.f;
            #pragma unroll 8
            for (int k = 0; k < 64; ++k) v += arena[1360+k] * Va[k*D + lane];
            float m = v;
            #pragma unroll
            for (int o = 32; o > 0; o >>= 1) m = fmaxf(m, __shfl_xor(m, o));
            float e = expf(v - m);
            float ss = e;
            #pragma unroll
            for (int o = 32; o > 0; o >>= 1) ss += __shfl_xor(ss, o);
            float val = (e / ss) * arena[lane];   // x part of hcx
            unsigned short hi = f2bf(val);
            unsigned short lo = f2bf(val - bf2f(hi));
            st_sc_s1(xHi + (size_t)row*D + lane, hi);
            st_sc_s1(xLo + (size_t)row*D + lane, lo);
            drain_stores();
            if (lane == 0) bump_flag(xflag);
        }

        // ---- Phase B: gate GEMM (R7 body, sc staging) ----
        {
            const unsigned short* ph = hHiR + (size_t)(b0+srow)*H + q4*16;
            const unsigned short* pl = hLoR + (size_t)(b0+srow)*H + q4*16;
            short8 h0,h1,l0,l1;
            ld_sc_4x16(ph, pl, h0, h1, l0, l1);
            *(short8*)&aHi[0][srow][q4*16]     = h0;
            *(short8*)&aHi[0][srow][q4*16 + 8] = h1;
            *(short8*)&aLo[0][srow][q4*16]     = l0;
            *(short8*)&aLo[0][srow][q4*16 + 8] = l1;
        }
        __syncthreads();

        f32x4 acc0 = {0,0,0,0}, acc1 = {0,0,0,0};

        for (int kb = 0; kb < 9; ++kb) {
            if (kb == 7) wait_flag(xflag, tgt);    // x_att ready (overlapped)
            const int cur = kb & 1;
            const unsigned short* pB = wswz + (size_t)(jt*9 + kb)*4096;
            short8 bh0 = *(const short8*)(pB + 0*2048 + 0*1024 + lofs);
            short8 bh1 = *(const short8*)(pB + 0*2048 + 1*1024 + lofs);
            short8 bl0 = *(const short8*)(pB + 1*2048 + 0*1024 + lofs);
            short8 bl1 = *(const short8*)(pB + 1*2048 + 1*1024 + lofs);
            if (kb < 8) {
                const unsigned short *ph, *pl;
                if (kb + 1 < 8) {
                    const size_t base = (size_t)(b0+srow)*H + (kb+1)*64 + q4*16;
                    ph = hHiR + base; pl = hLoR + base;
                } else {
                    const size_t base = (size_t)(b0+srow)*D + q4*16;
                    ph = xHi + base; pl = xLo + base;
                }
                short8 h0,h1,l0,l1;
                ld_sc_4x16(ph, pl, h0, h1, l0, l1);
                *(short8*)&aHi[cur^1][srow][q4*16]     = h0;
                *(short8*)&aHi[cur^1][srow][q4*16 + 8] = h1;
                *(short8*)&aLo[cur^1][srow][q4*16]     = l0;
                *(short8*)&aLo[cur^1][srow][q4*16 + 8] = l1;
            }
            const int ar = wr*32 + l15;
            short8 ah00 = *(const short8*)&aHi[cur][ar     ][cgi*8];
            short8 ah01 = *(const short8*)&aHi[cur][ar     ][32 + cgi*8];
            short8 ah10 = *(const short8*)&aHi[cur][ar + 16][cgi*8];
            short8 ah11 = *(const short8*)&aHi[cur][ar + 16][32 + cgi*8];
            short8 al00 = *(const short8*)&aLo[cur][ar     ][cgi*8];
            short8 al01 = *(const short8*)&aLo[cur][ar     ][32 + cgi*8];
            short8 al10 = *(const short8*)&aLo[cur][ar + 16][cgi*8];
            short8 al11 = *(const short8*)&aLo[cur][ar + 16][32 + cgi*8];

            acc0 = __builtin_amdgcn_mfma_f32_16x16x32_bf16(ah00, bh0, acc0, 0,0,0);
            acc1 = __builtin_amdgcn_mfma_f32_16x16x32_bf16(ah10, bh0, acc1, 0,0,0);
            acc0 = __builtin_amdgcn_mfma_f32_16x16x32_bf16(ah00, bl0, acc0, 0,0,0);
            acc1 = __builtin_amdgcn_mfma_f32_16x16x32_bf16(ah10, bl0, acc1, 0,0,0);
            acc0 = __builtin_amdgcn_mfma_f32_16x16x32_bf16(al00, bh0, acc0, 0,0,0);
            acc1 = __builtin_amdgcn_mfma_f32_16x16x32_bf16(al10, bh0, acc1, 0,0,0);
            acc0 = __builtin_amdgcn_mfma_f32_16x16x32_bf16(ah01, bh1, acc0, 0,0,0);
            acc1 = __builtin_amdgcn_mfma_f32_16x16x32_bf16(ah11, bh1, acc1, 0,0,0);
            acc0 = __builtin_amdgcn_mfma_f32_16x16x32_bf16(ah01, bl1, acc0, 0,0,0);
            acc1 = __builtin_amdgcn_mfma_f32_16x16x32_bf16(ah11, bl1, acc1, 0,0,0);
            acc0 = __builtin_amdgcn_mfma_f32_16x16x32_bf16(al01, bh1, acc0, 0,0,0);
            acc1 = __builtin_amdgcn_mfma_f32_16x16x32_bf16(al11, bh1, acc1, 0,0,0);
            __syncthreads();
        }

        {   // D layout: row = cgi*4 + r, col = l15 per 16x16 tile
            const int m0 = cgi * 4;
            #pragma unroll
            for (int r = 0; r < 4; ++r) {
                gout[wr*32 + m0 + r     ][wc*16 + l15] = acc0[r];
                gout[wr*32 + 16 + m0 + r][wc*16 + l15] = acc1[r];
            }
        }
        __syncthreads();
        {   // fused LSTM update (own unit slice, all 64 group rows)
            const int u8 = tid & 7;
            const int u_glob = jt*8 + u8;
            const float bs0 = bih[0*H + u_glob] + bhh[0*H + u_glob];
            const float bs1 = bih[1*H + u_glob] + bhh[1*H + u_glob];
            const float bs2 = bih[2*H + u_glob] + bhh[2*H + u_glob];
            const float bs3 = bih[3*H + u_glob] + bhh[3*H + u_glob];
            #pragma unroll
            for (int pp = 0; pp < 2; ++pp) {
                const int row_loc = (tid >> 3) + pp*32;
                const int b = b0 + row_loc;
                float gi  = gout[row_loc][u8*4 + 0] + bs0;
                float gf  = gout[row_loc][u8*4 + 1] + bs1;
                float ggt = gout[row_loc][u8*4 + 2] + bs2;
                float go  = gout[row_loc][u8*4 + 3] + bs3;
                const size_t idx = (size_t)b*H + u_glob;
                float c_old = ld_sc_f1(c32 + idx);
                float si = 1.f/(1.f + expf(-gi));
                float sf = 1.f/(1.f + expf(-gf));
                float so = 1.f/(1.f + expf(-go));
                float cn = sf*c_old + si*tanhf(ggt);
                float hn = so*tanhf(cn);
                st_sc_f1(c32 + idx, cn);
                st_sc_f1(h32 + (size_t)wrs*BH + idx, hn);
                unsigned short hi = f2bf(hn);
                unsigned short lo = f2bf(hn - bf2f(hi));
                st_sc_s1(hHi + (size_t)wrs*BH + idx, hi);
                st_sc_s1(hLo + (size_t)wrs*BH + idx, lo);
            }
        }
        drain_stores();
        __syncthreads();
        if (tid == 0) bump_flag(hflag);
    }
}

__global__ __launch_bounds__(256) void fc_kernel(
    const float* __restrict__ fcw, const float* __restrict__ fcb,
    const float* __restrict__ h32, float* __restrict__ out)
{
    const int b = blockIdx.x;
    __shared__ float hrow[H];
    const float* __restrict__ hp = h32 + (size_t)b*H;   // final h in slot 0
    for (int k = threadIdx.x; k < H; k += 256) hrow[k] = hp[k];
    __syncthreads();
    int j = threadIdx.x;
    if (j < 24) {
        float a = fcb[j];
        #pragma unroll 8
        for (int k = 0; k < H; ++k) a += hrow[k] * fcw[j*H + k];
        out[b*24 + j] = a;
    }
}

extern "C" void kernel_launch(void* const* d_in, const int* in_sizes, int n_in,
                              void* d_out, int out_size, void* d_ws, size_t ws_size,
                              hipStream_t stream) {
    const float* x   = (const float*)d_in[0];
    const float* Wa  = (const float*)d_in[1];
    const float* Ua  = (const float*)d_in[2];
    const float* ba  = (const float*)d_in[3];
    const float* Va  = (const float*)d_in[4];
    const float* Wih = (const float*)d_in[5];
    const float* Whh = (const float*)d_in[6];
    const float* bih = (const float*)d_in[7];
    const float* bhh = (const float*)d_in[8];
    const float* fcw = (const float*)d_in[9];
    const float* fcb = (const float*)d_in[10];
    float* out = (float*)d_out;

    char* base = (char*)d_ws;
    float* h32 = (float*)(base);                                    // 2MB
    float* c32 = (float*)(base + (size_t)2*BH*4);                   // 1MB
    unsigned short* hHi = (unsigned short*)(base + (size_t)3*BH*4); // 1MB
    unsigned short* hLo = hHi + (size_t)2*BH;                       // 1MB
    unsigned short* xHi = hLo + (size_t)2*BH;                       // 64KB
    unsigned short* xLo = xHi + (size_t)B*D;                        // 64KB
    unsigned short* wswz = xLo + (size_t)B*D;                       // 4.5MB
    unsigned int* bar = (unsigned int*)(wswz + (size_t)576*4096);   // 1KB
    const size_t NEED = ((char*)bar - base) + 1024;

    hipLaunchKernelGGL(prep_weights, dim3(64, 9), dim3(256), 0, stream,
                       Whh, Wih, wswz);

    bool coop = (ws_size >= NEED);
    if (coop) {
        int maxBlk = 0;
        hipError_t oe = hipOccupancyMaxActiveBlocksPerMultiprocessor(
            &maxBlk, persist_kernel, 256, 0);
        coop = (oe == hipSuccess && maxBlk >= 2);
    }
    if (coop) {
        hipMemsetAsync(bar, 0, 1024, stream);
        void* args[] = {
            (void*)&x, (void*)&Wa, (void*)&Ua, (void*)&ba, (void*)&Va,
            (void*)&wswz, (void*)&hHi, (void*)&hLo, (void*)&xHi, (void*)&xLo,
            (void*)&h32, (void*)&c32, (void*)&bih, (void*)&bhh, (void*)&bar
        };
        hipError_t rc = hipLaunchCooperativeKernel((void*)persist_kernel,
                            dim3(512), dim3(256), args, 0, stream);
        if (rc != hipSuccess) coop = false;
    }
    if (!coop) {   // fallback: proven multi-kernel path (R7)
        hipLaunchKernelGGL(init_zero, dim3((BH + 255)/256), dim3(256), 0, stream,
                           h32, c32, hHi, hLo);
        for (int t = 0; t < S; ++t) {
            hipLaunchKernelGGL(attn_kernel, dim3(B/2), dim3(256), 0, stream,
                               x, Wa, Ua, ba, Va, h32, c32, xHi, xLo, t);
            hipLaunchKernelGGL(gates_kernel, dim3(64, 8), dim3(256), 0, stream,
                               wswz, hHi, hLo, xHi, xLo, h32, c32, bih, bhh, t);
        }
    }
    hipLaunchKernelGGL(fc_kernel, dim3(B), dim3(256), 0, stream, fcw, fcb, h32, out);
}

// Round 12
// 7906.226 us; speedup vs baseline: 4.6209x; 1.0892x over previous
//
#include <hip/hip_runtime.h>
#include <math.h>

#define B 512
#define S 256
#define D 64
#define H 512
#define BH (B*H)

typedef __attribute__((ext_vector_type(8))) short short8;
typedef __attribute__((ext_vector_type(4))) float f32x4;
typedef __attribute__((ext_vector_type(4))) unsigned int uint4v;

__device__ inline unsigned short f2bf(float v) {            // fp32 -> bf16 RNE
    unsigned int u = __float_as_uint(v);
    unsigned int r = (u + 0x7fffu + ((u >> 16) & 1u)) >> 16;
    return (unsigned short)r;
}
__device__ inline float bf2f(unsigned short b) {
    return __uint_as_float(((unsigned int)b) << 16);
}

// ws layout: h32[2*BH f32] | c32[BH f32] | xatt[B*D f32] | wswz[576*4096 u16]

__global__ __launch_bounds__(256) void init_zero(
    float* __restrict__ h32, float* __restrict__ c32)
{
    int i = blockIdx.x * blockDim.x + threadIdx.x;
    if (i < BH) { h32[i] = 0.f; c32[i] = 0.f; }
}

// Pre-split Whh/Wih -> RNE bf16 hi/lo fragment slabs (one-time).
// Slab per (jt,kb): [half2][ks2][cg4][jj32][8] shorts = 4096 shorts (8 KB).
// j global = jt*32 + jj, encoded j = u*4 + q (u = unit, q = gate).
__global__ __launch_bounds__(256) void prep_weights(
    const float* __restrict__ Whh, const float* __restrict__ Wih,
    unsigned short* __restrict__ wswz)
{
    const int jt = blockIdx.x;
    const int kb = blockIdx.y;
    const int t = threadIdx.x;
    const int jj = t >> 3;
    const int kk8 = t & 7;
    const int jg = jt*32 + jj;
    const int u = jg >> 2, q = jg & 3;
    const int Wrow = q*H + u;

    const float* src = (kb < 8) ? (Whh + (size_t)Wrow*H + kb*64 + kk8*8)
                                : (Wih + (size_t)Wrow*D + kk8*8);
    float v[8];
    *(float4*)&v[0] = *(const float4*)(src);
    *(float4*)&v[4] = *(const float4*)(src + 4);

    unsigned short hi[8], lo[8];
    #pragma unroll
    for (int e = 0; e < 8; ++e) {
        hi[e] = f2bf(v[e]);
        lo[e] = f2bf(v[e] - bf2f(hi[e]));
    }
    const int ks = kk8 >> 2, cg2 = kk8 & 3;
    const size_t slab = (size_t)(jt*9 + kb) * 4096;
    *(short8*)(wswz + slab + (size_t)(0*2048 + ks*1024 + cg2*256 + jj*8)) = *(const short8*)hi;
    *(short8*)(wswz + slab + (size_t)(1*2048 + ks*1024 + cg2*256 + jj*8)) = *(const short8*)lo;
}

// Attention gate — R2 VERBATIM (measured 4.8us worst / ~3us avg). 2 rows/WG.
__global__ __launch_bounds__(256) void attn_kernel(
    const float* __restrict__ x, const float* __restrict__ Wa,
    const float* __restrict__ Ua, const float* __restrict__ ba,
    const float* __restrict__ Va,
    const float* __restrict__ h32, const float* __restrict__ c32,
    float* __restrict__ xatt, int t)
{
    const int d = threadIdx.x & 63;
    const int r = (threadIdx.x >> 6) & 1;
    const int p = threadIdx.x >> 7;
    const int b = blockIdx.x * 2 + r;

    const int rd = t & 1;
    const float* __restrict__ hrow = h32 + (size_t)rd*BH + (size_t)b*H;
    const float* __restrict__ crow = c32 + (size_t)b*H;
    const float* __restrict__ xrow = x + ((size_t)b*S + t)*D;

    __shared__ float part[2][2][64];
    __shared__ float ta[2][64];
    __shared__ float pv[2][2][64];

    float a = 0.f;
    if (p == 0) {
        a = ba[d];
        #pragma unroll 8
        for (int k = 0; k < D; ++k) a += xrow[k] * Wa[k*D + d];
        #pragma unroll 8
        for (int k = 0; k < H; ++k) a += hrow[k] * Ua[k*D + d];
    } else {
        #pragma unroll 8
        for (int k = 0; k < H; ++k) a += crow[k] * Ua[(size_t)(H + k)*D + d];
    }
    part[r][p][d] = a;
    __syncthreads();
    if (p == 0) ta[r][d] = tanhf(part[r][0][d] + part[r][1][d]);
    __syncthreads();
    float av = 0.f;
    {
        const int k0 = p * 32;
        #pragma unroll 8
        for (int k = k0; k < k0 + 32; ++k) av += ta[r][k] * Va[k*D + d];
    }
    pv[r][p][d] = av;
    __syncthreads();
    float v = pv[r][0][d] + pv[r][1][d];
    float m = v;
    #pragma unroll
    for (int o = 32; o > 0; o >>= 1) m = fmaxf(m, __shfl_xor(m, o));
    float e = expf(v - m);
    float ssum = e;
    #pragma unroll
    for (int o = 32; o > 0; o >>= 1) ssum += __shfl_xor(ssum, o);
    if (p == 0) {
        xatt[(size_t)b*D + d] = (e / ssum) * xrow[d];
    }
}

// Gate GEMM via MFMA 3-pass. fp32 interfaces (h32/c32/xatt like R2); A split
// to bf16 hi/lo IN-REGISTER during staging (trunc split, packed u32 writes).
// grid (64 jt, 8 rt), 256 thr, 4 waves 2x2 (wr: 32-row half, wc: 16-j half).
__global__ __launch_bounds__(256, 2) void gates_kernel(
    const unsigned short* __restrict__ wswz,
    const float* __restrict__ xatt,
    float* __restrict__ h32, float* __restrict__ c32,
    const float* __restrict__ bih, const float* __restrict__ bhh, int t)
{
    const int tid = threadIdx.x;
    const int lane = tid & 63;
    const int wid = tid >> 6;
    const int wr = wid >> 1, wc = wid & 1;
    const int jt = blockIdx.x;
    const int b0 = blockIdx.y * 64;
    const int l15 = lane & 15;
    const int cgi = lane >> 4;

    __shared__ __align__(16) unsigned short aHi[2][64][72];
    __shared__ __align__(16) unsigned short aLo[2][64][72];
    __shared__ float gout[64][37];

    const int rd = t & 1, wrs = rd ^ 1;
    const float* __restrict__ h32r = h32 + (size_t)rd*BH;

    const int srow = tid >> 2;      // 0..63 (staged row)
    const int q4 = tid & 3;         // 16-elem col group

    // load 16 fp32, trunc-split into packed bf16 hi/lo, store 2x16B per plane
    auto stage = [&](const float* src, int buf) {
        float v[16];
        #pragma unroll
        for (int i = 0; i < 4; ++i)
            *(float4*)&v[i*4] = *(const float4*)(src + i*4);
        unsigned int hp[8], lp[8];
        #pragma unroll
        for (int w = 0; w < 8; ++w) {
            unsigned int ue = __float_as_uint(v[2*w]);
            unsigned int uo = __float_as_uint(v[2*w+1]);
            hp[w] = (ue >> 16) | (uo & 0xFFFF0000u);
            float le = v[2*w]   - __uint_as_float(ue & 0xFFFF0000u);
            float lq = v[2*w+1] - __uint_as_float(uo & 0xFFFF0000u);
            lp[w] = (__float_as_uint(le) >> 16) | (__float_as_uint(lq) & 0xFFFF0000u);
        }
        *(uint4v*)&aHi[buf][srow][q4*16]     = *(uint4v*)&hp[0];
        *(uint4v*)&aHi[buf][srow][q4*16 + 8] = *(uint4v*)&hp[4];
        *(uint4v*)&aLo[buf][srow][q4*16]     = *(uint4v*)&lp[0];
        *(uint4v*)&aLo[buf][srow][q4*16 + 8] = *(uint4v*)&lp[4];
    };

    stage(h32r + (size_t)(b0 + srow)*H + q4*16, 0);   // chunk 0
    __syncthreads();

    f32x4 acc0 = {0,0,0,0}, acc1 = {0,0,0,0};
    const int lofs = cgi*256 + (wc*16 + l15)*8;

    for (int kb = 0; kb < 9; ++kb) {
        const int cur = kb & 1;
        const unsigned short* pB = wswz + (size_t)(jt*9 + kb)*4096;
        short8 bh0 = *(const short8*)(pB + 0*2048 + 0*1024 + lofs);
        short8 bh1 = *(const short8*)(pB + 0*2048 + 1*1024 + lofs);
        short8 bl0 = *(const short8*)(pB + 1*2048 + 0*1024 + lofs);
        short8 bl1 = *(const short8*)(pB + 1*2048 + 1*1024 + lofs);
        if (kb < 8) {
            const float* nsrc = (kb + 1 < 8)
                ? (h32r + (size_t)(b0 + srow)*H + (kb + 1)*64 + q4*16)
                : (xatt + (size_t)(b0 + srow)*D + q4*16);
            stage(nsrc, cur ^ 1);
        }
        const int ar = wr*32 + l15;
        short8 ah00 = *(const short8*)&aHi[cur][ar     ][cgi*8];
        short8 ah01 = *(const short8*)&aHi[cur][ar     ][32 + cgi*8];
        short8 ah10 = *(const short8*)&aHi[cur][ar + 16][cgi*8];
        short8 ah11 = *(const short8*)&aHi[cur][ar + 16][32 + cgi*8];
        short8 al00 = *(const short8*)&aLo[cur][ar     ][cgi*8];
        short8 al01 = *(const short8*)&aLo[cur][ar     ][32 + cgi*8];
        short8 al10 = *(const short8*)&aLo[cur][ar + 16][cgi*8];
        short8 al11 = *(const short8*)&aLo[cur][ar + 16][32 + cgi*8];

        acc0 = __builtin_amdgcn_mfma_f32_16x16x32_bf16(ah00, bh0, acc0, 0,0,0);
        acc1 = __builtin_amdgcn_mfma_f32_16x16x32_bf16(ah10, bh0, acc1, 0,0,0);
        acc0 = __builtin_amdgcn_mfma_f32_16x16x32_bf16(ah00, bl0, acc0, 0,0,0);
        acc1 = __builtin_amdgcn_mfma_f32_16x16x32_bf16(ah10, bl0, acc1, 0,0,0);
        acc0 = __builtin_amdgcn_mfma_f32_16x16x32_bf16(al00, bh0, acc0, 0,0,0);
        acc1 = __builtin_amdgcn_mfma_f32_16x16x32_bf16(al10, bh0, acc1, 0,0,0);
        acc0 = __builtin_amdgcn_mfma_f32_16x16x32_bf16(ah01, bh1, acc0, 0,0,0);
        acc1 = __builtin_amdgcn_mfma_f32_16x16x32_bf16(ah11, bh1, acc1, 0,0,0);
        acc0 = __builtin_amdgcn_mfma_f32_16x16x32_bf16(ah01, bl1, acc0, 0,0,0);
        acc1 = __builtin_amdgcn_mfma_f32_16x16x32_bf16(ah11, bl1, acc1, 0,0,0);
        acc0 = __builtin_amdgcn_mfma_f32_16x16x32_bf16(al01, bh1, acc0, 0,0,0);
        acc1 = __builtin_amdgcn_mfma_f32_16x16x32_bf16(al11, bh1, acc1, 0,0,0);
        __syncthreads();
    }

    {   // D layout: row = cgi*4 + r, col = l15 per 16x16 tile (m89-verified)
        const int m0 = cgi * 4;
        #pragma unroll
        for (int r = 0; r < 4; ++r) {
            gout[wr*32 + m0 + r     ][wc*16 + l15] = acc0[r];
            gout[wr*32 + 16 + m0 + r][wc*16 + l15] = acc1[r];
        }
    }
    __syncthreads();
    {   // fused LSTM update: 64 rows x 8 units; writes h32 slot wrs + c32
        const int u8 = tid & 7;
        const int u_glob = jt*8 + u8;
        const float bs0 = bih[0*H + u_glob] + bhh[0*H + u_glob];
        const float bs1 = bih[1*H + u_glob] + bhh[1*H + u_glob];
        const float bs2 = bih[2*H + u_glob] + bhh[2*H + u_glob];
        const float bs3 = bih[3*H + u_glob] + bhh[3*H + u_glob];
        float* __restrict__ h32w = h32 + (size_t)wrs*BH;
        #pragma unroll
        for (int pp = 0; pp < 2; ++pp) {
            const int row_loc = (tid >> 3) + pp*32;
            const int b = b0 + row_loc;
            float gi = gout[row_loc][u8*4 + 0] + bs0;
            float gf = gout[row_loc][u8*4 + 1] + bs1;
            float gg = gout[row_loc][u8*4 + 2] + bs2;
            float go = gout[row_loc][u8*4 + 3] + bs3;
            const size_t idx = (size_t)b*H + u_glob;
            float c_old = c32[idx];
            float si = 1.f/(1.f + expf(-gi));
            float sf = 1.f/(1.f + expf(-gf));
            float so = 1.f/(1.f + expf(-go));
            float cn = sf*c_old + si*tanhf(gg);
            float hn = so*tanhf(cn);
            c32[idx] = cn;
            h32w[idx] = hn;
        }
    }
}

__global__ __launch_bounds__(256) void fc_kernel(
    const float* __restrict__ fcw, const float* __restrict__ fcb,
    const float* __restrict__ h32, float* __restrict__ out)
{
    const int b = blockIdx.x;
    __shared__ float hrow[H];
    const float* __restrict__ hp = h32 + (size_t)b*H;   // final h in slot 0 (S even)
    for (int k = threadIdx.x; k < H; k += 256) hrow[k] = hp[k];
    __syncthreads();
    int j = threadIdx.x;
    if (j < 24) {
        float a = fcb[j];
        #pragma unroll 8
        for (int k = 0; k < H; ++k) a += hrow[k] * fcw[j*H + k];
        out[b*24 + j] = a;
    }
}

extern "C" void kernel_launch(void* const* d_in, const int* in_sizes, int n_in,
                              void* d_out, int out_size, void* d_ws, size_t ws_size,
                              hipStream_t stream) {
    const float* x   = (const float*)d_in[0];
    const float* Wa  = (const float*)d_in[1];
    const float* Ua  = (const float*)d_in[2];
    const float* ba  = (const float*)d_in[3];
    const float* Va  = (const float*)d_in[4];
    const float* Wih = (const float*)d_in[5];
    const float* Whh = (const float*)d_in[6];
    const float* bih = (const float*)d_in[7];
    const float* bhh = (const float*)d_in[8];
    const float* fcw = (const float*)d_in[9];
    const float* fcb = (const float*)d_in[10];
    float* out = (float*)d_out;

    char* base = (char*)d_ws;
    float* h32  = (float*)(base);                                   // 2*BH f32
    float* c32  = (float*)(base + (size_t)2*BH*4);                  // BH f32
    float* xatt = (float*)(base + (size_t)3*BH*4);                  // B*D f32
    unsigned short* wswz = (unsigned short*)(base + (size_t)3*BH*4 + (size_t)B*D*4);

    hipLaunchKernelGGL(init_zero, dim3((BH + 255)/256), dim3(256), 0, stream,
                       h32, c32);
    hipLaunchKernelGGL(prep_weights, dim3(64, 9), dim3(256), 0, stream,
                       Whh, Wih, wswz);
    for (int t = 0; t < S; ++t) {
        hipLaunchKernelGGL(attn_kernel, dim3(B/2), dim3(256), 0, stream,
                           x, Wa, Ua, ba, Va, h32, c32, xatt, t);
        hipLaunchKernelGGL(gates_kernel, dim3(64, 8), dim3(256), 0, stream,
                           wswz, xatt, h32, c32, bih, bhh, t);
    }
    hipLaunchKernelGGL(fc_kernel, dim3(B), dim3(256), 0, stream, fcw, fcb, h32, out);
}